// Round 1
// baseline (1513.102 us; speedup 1.0000x reference)
//
#include <hip/hip_runtime.h>

#define BATCH 4
#define CH    128
#define NPTS  2000
#define KNN   9
#define NHEAD 4
#define HD    32

// ---- workspace layout (float offsets) ----
#define OFF_XT    0          // (B,N,128) transposed x
#define OFF_YT    1024000    // (B,N,128) transposed y
#define OFF_PT    2048000    // P = (W1a+W1b)x + b1f   ; later reused as Q_att, then T_t half
#define OFF_QT    3072000    // Q = W1b x              ; later reused as K_att, then T_t half
#define OFF_AGG   4096000    // edge-conv output m1 (B,N,128)
#define OFF_MH    5120000    // wmh output
#define OFF_MISC  6144000
#define OFF_W1SUM (OFF_MISC)
#define OFF_W1B   (OFF_MISC+16384)
#define OFF_W2T   (OFF_MISC+32768)
#define OFF_WQT   (OFF_MISC+49152)
#define OFF_WKT   (OFF_MISC+65536)
#define OFF_WVT   (OFF_MISC+81920)
#define OFF_WMHT  (OFF_MISC+98304)
#define OFF_WC1T  (OFF_MISC+114688)   // 256x256
#define OFF_WC2T  (OFF_MISC+180224)   // 256x128
#define OFF_B1F   (OFF_MISC+212992)
#define OFF_B2F   (OFF_MISC+213120)
#define OFF_BC1F  (OFF_MISC+213248)
#define OFF_XX    (OFF_MISC+213504)   // B*N sums of squares
#define OFF_IDX   (OFF_MISC+221504)   // B*N*9 ints
// total ~6,437,504 floats = 25.8 MB

// ---------------- weight prep: transpose + BN folding ----------------
__global__ __launch_bounds__(256) void prep_kernel(
    const float* __restrict__ w1, const float* __restrict__ b1,
    const float* __restrict__ g1, const float* __restrict__ be1,
    const float* __restrict__ w2, const float* __restrict__ b2,
    const float* __restrict__ g2, const float* __restrict__ be2,
    const float* __restrict__ wq, const float* __restrict__ wk,
    const float* __restrict__ wv, const float* __restrict__ wmh,
    const float* __restrict__ wc1, const float* __restrict__ bc1,
    const float* __restrict__ cg, const float* __restrict__ cbe,
    const float* __restrict__ wc2, float* __restrict__ ws)
{
    int id = blockIdx.x * 256 + threadIdx.x;   // 65536 threads
    const float rs = rsqrtf(1.f + 1e-5f);
    if (id < 16384) {
        int c = id >> 7, o = id & 127;
        float s1 = g1[o] * rs;
        ws[OFF_W1SUM + id] = (w1[o*256 + c] + w1[o*256 + 128 + c]) * s1;
        ws[OFF_W1B   + id] = w1[o*256 + 128 + c] * s1;
        float s2 = g2[o] * rs;
        ws[OFF_W2T   + id] = w2[o*128 + c] * s2;
        ws[OFF_WQT   + id] = wq[o*128 + c];
        ws[OFF_WKT   + id] = wk[o*128 + c];
        ws[OFF_WVT   + id] = wv[o*128 + c];
        ws[OFF_WMHT  + id] = wmh[o*128 + c];
    }
    if (id < 32768) {
        int c = id >> 7, o = id & 127;           // wc2 (128,256) -> [c][o]
        ws[OFF_WC2T + id] = wc2[o*256 + c];
    }
    {   // wc1 (256,256) -> [c][o], scaled
        int c = id >> 8, o = id & 255;
        ws[OFF_WC1T + id] = wc1[o*256 + c] * (cg[o] * rs);
    }
    if (id < 128) {
        float s1 = g1[id] * rs, s2 = g2[id] * rs;
        ws[OFF_B1F + id] = b1[id]*s1 + be1[id];
        ws[OFF_B2F + id] = b2[id]*s2 + be2[id];
    }
    if (id < 256) {
        ws[OFF_BC1F + id] = bc1[id]*(cg[id]*rs) + cbe[id];
    }
}

// ---------------- transpose (B,C,N)->(B,N,C), optional xx ----------------
__global__ __launch_bounds__(128) void transpose_kernel(
    const float* __restrict__ src, float* __restrict__ dst, float* __restrict__ xx)
{
    int blk = blockIdx.x; int b = blk / NPTS, n = blk % NPTS;
    int c = threadIdx.x;
    float v = src[((size_t)b*CH + c)*NPTS + n];
    dst[((size_t)b*NPTS + n)*CH + c] = v;
    if (xx) {
        __shared__ float red[128];
        red[c] = v*v;
        __syncthreads();
        for (int s = 64; s > 0; s >>= 1) { if (c < s) red[c] += red[c+s]; __syncthreads(); }
        if (c == 0) xx[b*NPTS + n] = red[0];
    }
}

// ---------------- KNN top-9 ----------------
__global__ __launch_bounds__(256) void knn_kernel(
    const float* __restrict__ Xt, const float* __restrict__ xx, int* __restrict__ idxOut)
{
    __shared__ float ctr[8][128];
    __shared__ float xm[32][132];   // padded
    int b = blockIdx.y, n0 = blockIdx.x * 8;
    int tid = threadIdx.x;
    int g = tid >> 5, ml = tid & 31;
    for (int i = tid; i < 8*128; i += 256) {
        int j = i >> 7, c = i & 127;
        ctr[j][c] = Xt[((size_t)b*NPTS + n0 + j)*128 + c];
    }
    int n = n0 + g;
    float xxn = xx[b*NPTS + n];
    float vals[9]; int ids[9];
#pragma unroll
    for (int k = 0; k < 9; k++) { vals[k] = -3.4e38f; ids[k] = -1; }
    float vmin = -3.4e38f; int amin = 0;

    for (int m0 = 0; m0 < NPTS; m0 += 32) {
        __syncthreads();
        for (int i = tid; i < 32*128; i += 256) {
            int mm = i >> 7, c = i & 127;
            int m = m0 + mm;
            xm[mm][c] = (m < NPTS) ? Xt[((size_t)b*NPTS + m)*128 + c] : 0.f;
        }
        __syncthreads();
        int m = m0 + ml;
        const float4* xr = (const float4*)&xm[ml][0];
        const float4* cr = (const float4*)&ctr[g][0];
        float dot = 0.f;
#pragma unroll
        for (int c4 = 0; c4 < 32; c4++) {
            float4 a = xr[c4], q = cr[c4];
            dot += a.x*q.x + a.y*q.y + a.z*q.z + a.w*q.w;
        }
        float xxm = (m < NPTS) ? xx[b*NPTS + m] : 0.f;
        float d = (m < NPTS) ? (2.f*dot - xxn - xxm) : -3.4e38f;
        if (d > vmin) {
#pragma unroll
            for (int k = 0; k < 9; k++) {
                bool sel = (k == amin);
                vals[k] = sel ? d : vals[k];
                ids[k]  = sel ? m : ids[k];
            }
            vmin = vals[0]; amin = 0;
#pragma unroll
            for (int k = 1; k < 9; k++) {
                bool lt = vals[k] < vmin;
                vmin = lt ? vals[k] : vmin;
                amin = lt ? k : amin;
            }
        }
    }
    // merge top-9 across the 32 lanes of this group (all same n)
    unsigned used = 0;
    for (int r = 0; r < 9; r++) {
        float bv = -3.4e38f; int bm = -1;
#pragma unroll
        for (int k = 0; k < 9; k++) {
            bool ok = !(used & (1u << k)) && (vals[k] > bv);
            bv = ok ? vals[k] : bv;
            bm = ok ? ids[k]  : bm;
        }
        float v = bv; int mi = bm;
        for (int off = 16; off; off >>= 1) {
            float ov = __shfl_xor(v, off, 32);
            int  omi = __shfl_xor(mi, off, 32);
            if (ov > v || (ov == v && omi >= 0 && omi < mi)) { v = ov; mi = omi; }
        }
#pragma unroll
        for (int k = 0; k < 9; k++) {
            if (ids[k] == mi) { used |= (1u << k); }
        }
        if (ml == 0) idxOut[((size_t)b*NPTS + n)*KNN + r] = mi;
    }
}

// ---------------- dual GEMM: Out{A,B}[row][o] = sum_c In[row][c]*W{a,b}[c][o] + bias ----------------
__global__ __launch_bounds__(128) void gemm_dual_kernel(
    const float* __restrict__ In, const float* __restrict__ Wa, const float* __restrict__ Wb,
    const float* __restrict__ ba, const float* __restrict__ bb,
    float* __restrict__ OutA, float* __restrict__ OutB)
{
    __shared__ float in_lds[8][128];
    int row0 = blockIdx.x * 8, tid = threadIdx.x;
    const float* src = In + (size_t)row0 * 128;
    for (int i = tid; i < 1024; i += 128) ((float*)in_lds)[i] = src[i];
    __syncthreads();
    float accA[8], accB[8];
    float bA = ba ? ba[tid] : 0.f, bB = bb ? bb[tid] : 0.f;
#pragma unroll
    for (int j = 0; j < 8; j++) { accA[j] = bA; accB[j] = bB; }
    for (int c = 0; c < 128; c++) {
        float wa = Wa[c*128 + tid], wb = Wb[c*128 + tid];
#pragma unroll
        for (int j = 0; j < 8; j++) {
            float x = in_lds[j][c];
            accA[j] += x * wa;
            accB[j] += x * wb;
        }
    }
#pragma unroll
    for (int j = 0; j < 8; j++) {
        OutA[(size_t)(row0 + j)*128 + tid] = accA[j];
        OutB[(size_t)(row0 + j)*128 + tid] = accB[j];
    }
}

// ---------------- generic GEMM ----------------
template<int CIN, int COUT, bool RELU, bool TRANSOUT, bool HASRES, bool CONCAT>
__global__ __launch_bounds__(COUT) void gemmT_kernel(
    const float* __restrict__ In, const float* __restrict__ In2,
    const float* __restrict__ Wt, const float* __restrict__ bias,
    const float* __restrict__ Res, float* __restrict__ Out)
{
    __shared__ float in_lds[8][CIN];
    int row0 = blockIdx.x * 8, tid = threadIdx.x;
    if (!CONCAT) {
        const float* src = In + (size_t)row0 * CIN;
        for (int i = tid; i < 8*CIN; i += COUT) ((float*)in_lds)[i] = src[i];
    } else {
        for (int i = tid; i < 8*128; i += COUT) {
            int j = i >> 7, c = i & 127;
            in_lds[j][c]       = In [(size_t)(row0 + j)*128 + c];
            in_lds[j][128 + c] = In2[(size_t)(row0 + j)*128 + c];
        }
    }
    __syncthreads();
    float acc[8];
    float b = bias ? bias[tid] : 0.f;
#pragma unroll
    for (int j = 0; j < 8; j++) acc[j] = b;
    for (int c = 0; c < CIN; c++) {
        float w = Wt[c*COUT + tid];
#pragma unroll
        for (int j = 0; j < 8; j++) acc[j] += in_lds[j][c] * w;
    }
#pragma unroll
    for (int j = 0; j < 8; j++) {
        float v = acc[j];
        if (RELU) v = fmaxf(v, 0.f);
        size_t row = row0 + j;
        if (HASRES) v += Res[row*COUT + tid];
        if (!TRANSOUT) {
            Out[row*COUT + tid] = v;
        } else {
            int b_ = (int)(row / NPTS), n_ = (int)(row % NPTS);
            Out[((size_t)b_*COUT + tid)*NPTS + n_] = v;
        }
    }
}

// ---------------- edge conv: gather + conv2(+bn+relu) + max over k ----------------
__global__ __launch_bounds__(128) void edgeconv_kernel(
    const float* __restrict__ Pt, const float* __restrict__ Qt,
    const int* __restrict__ idx, const float* __restrict__ W2t,
    const float* __restrict__ b2f, float* __restrict__ Agg)
{
    int blk = blockIdx.x; int b = blk / NPTS, n = blk % NPTS;
    int o = threadIdx.x;
    __shared__ float r[128*9];
    __shared__ int mk[9];
    if (o < 9) mk[o] = idx[((size_t)b*NPTS + n)*KNN + o];
    __syncthreads();
    float p = Pt[((size_t)b*NPTS + n)*128 + o];
#pragma unroll
    for (int k = 0; k < 9; k++) {
        float q = Qt[((size_t)b*NPTS + mk[k])*128 + o];
        r[o*9 + k] = fmaxf(p - q, 0.f);   // relu(bn1(conv1)) folded
    }
    __syncthreads();
    float acc[9];
#pragma unroll
    for (int k = 0; k < 9; k++) acc[k] = 0.f;
    for (int c = 0; c < 128; c++) {
        float w = W2t[c*128 + o];
#pragma unroll
        for (int k = 0; k < 9; k++) acc[k] += r[c*9 + k] * w;
    }
    float bb = b2f[o];
    float vmax = -3.4e38f;
#pragma unroll
    for (int k = 0; k < 9; k++) vmax = fmaxf(vmax, fmaxf(acc[k] + bb, 0.f));
    Agg[((size_t)b*NPTS + n)*128 + o] = vmax;
}

// ---------------- attention core ----------------
__global__ __launch_bounds__(256) void attn_kernel(
    const float* __restrict__ Q, const float* __restrict__ Kt,
    const float* __restrict__ Vt, float* __restrict__ Add)
{
    __shared__ float q[8][32];
    __shared__ float s[8][NPTS];
    __shared__ float rsum[8];
    int nt = blockIdx.x, h = blockIdx.y, b = blockIdx.z;
    int n0 = nt * 8;
    int tid = threadIdx.x;
    const float scale = 0.17677669529663687f;  // 1/sqrt(32)
    {
        int j = tid >> 5, d = tid & 31;
        q[j][d] = Q[((size_t)b*NPTS + n0 + j)*128 + h*32 + d] * scale;
    }
    __syncthreads();
    // phase 1: scores
    for (int m = tid; m < NPTS; m += 256) {
        const float4* kp = (const float4*)&Kt[((size_t)b*NPTS + m)*128 + h*32];
        float4 kv[8];
#pragma unroll
        for (int i = 0; i < 8; i++) kv[i] = kp[i];
#pragma unroll
        for (int j = 0; j < 8; j++) {
            const float4* qp = (const float4*)&q[j][0];
            float a = 0.f;
#pragma unroll
            for (int i = 0; i < 8; i++) {
                float4 qq = qp[i];
                a += qq.x*kv[i].x + qq.y*kv[i].y + qq.z*kv[i].z + qq.w*kv[i].w;
            }
            s[j][m] = a;
        }
    }
    __syncthreads();
    // phase 2: softmax (store unnormalized exp; 1/sum in rsum)
    int wave = tid >> 6, lane = tid & 63;
    for (int jj = 0; jj < 2; jj++) {
        int j = wave + jj*4;
        float mx = -3.4e38f;
        for (int m = lane; m < NPTS; m += 64) mx = fmaxf(mx, s[j][m]);
        for (int off = 32; off; off >>= 1) mx = fmaxf(mx, __shfl_xor(mx, off));
        float sum = 0.f;
        for (int m = lane; m < NPTS; m += 64) {
            float e = __expf(s[j][m] - mx);
            s[j][m] = e;
            sum += e;
        }
        for (int off = 32; off; off >>= 1) sum += __shfl_xor(sum, off);
        if (lane == 0) rsum[j] = 1.f / sum;
    }
    __syncthreads();
    // phase 3: P @ V
    int d = tid & 31, mg = tid >> 5;
    float acc[8];
#pragma unroll
    for (int j = 0; j < 8; j++) acc[j] = 0.f;
    for (int m = mg; m < NPTS; m += 8) {
        float v = Vt[((size_t)b*NPTS + m)*128 + h*32 + d];
#pragma unroll
        for (int j = 0; j < 8; j++) acc[j] += s[j][m] * v;
    }
    __syncthreads();
    float* red = &s[0][0];   // reuse: [mg][j][d]
#pragma unroll
    for (int j = 0; j < 8; j++) red[mg*256 + j*32 + d] = acc[j];
    __syncthreads();
    int j2 = tid >> 5;
    float t = 0.f;
#pragma unroll
    for (int m2 = 0; m2 < 8; m2++) t += red[m2*256 + j2*32 + d];
    t *= rsum[j2];
    Add[((size_t)b*NPTS + n0 + j2)*128 + h*32 + d] = t;
}

// ---------------- launcher ----------------
extern "C" void kernel_launch(void* const* d_in, const int* in_sizes, int n_in,
                              void* d_out, int out_size, void* d_ws, size_t ws_size,
                              hipStream_t stream)
{
    const float* x    = (const float*)d_in[0];
    const float* y    = (const float*)d_in[1];
    const float* w1   = (const float*)d_in[2];
    const float* b1   = (const float*)d_in[3];
    const float* g1   = (const float*)d_in[4];
    const float* be1  = (const float*)d_in[5];
    const float* w2   = (const float*)d_in[6];
    const float* b2   = (const float*)d_in[7];
    const float* g2   = (const float*)d_in[8];
    const float* be2  = (const float*)d_in[9];
    const float* wq   = (const float*)d_in[10];
    const float* bq   = (const float*)d_in[11];
    const float* wk   = (const float*)d_in[12];
    const float* bk   = (const float*)d_in[13];
    const float* wv   = (const float*)d_in[14];
    const float* bv   = (const float*)d_in[15];
    const float* wmh  = (const float*)d_in[16];
    const float* bmh  = (const float*)d_in[17];
    const float* wc1  = (const float*)d_in[18];
    const float* bc1  = (const float*)d_in[19];
    const float* cg   = (const float*)d_in[20];
    const float* cbe  = (const float*)d_in[21];
    const float* wc2  = (const float*)d_in[22];
    const float* bc2  = (const float*)d_in[23];
    float* ws = (float*)d_ws;
    float* out = (float*)d_out;

    float* XT  = ws + OFF_XT;
    float* YT  = ws + OFF_YT;
    float* PT  = ws + OFF_PT;
    float* QT  = ws + OFF_QT;
    float* AGG = ws + OFF_AGG;
    float* MH  = ws + OFF_MH;
    float* XX  = ws + OFF_XX;
    int*   IDX = (int*)(ws + OFF_IDX);
    // reuse:
    float* QA  = PT;   // after edgeconv
    float* KA  = QT;
    float* VA  = XT;
    float* ADD = YT;   // after k/v GEMM
    float* TT  = PT;   // 8000x256 spans PT+QT, after attention

    prep_kernel<<<256, 256, 0, stream>>>(w1, b1, g1, be1, w2, b2, g2, be2,
                                         wq, wk, wv, wmh, wc1, bc1, cg, cbe, wc2, ws);
    transpose_kernel<<<BATCH*NPTS, 128, 0, stream>>>(x, XT, XX);
    transpose_kernel<<<BATCH*NPTS, 128, 0, stream>>>(y, YT, nullptr);
    knn_kernel<<<dim3(NPTS/8, BATCH), 256, 0, stream>>>(XT, XX, IDX);
    gemm_dual_kernel<<<BATCH*NPTS/8, 128, 0, stream>>>(XT, ws + OFF_W1SUM, ws + OFF_W1B,
                                                       ws + OFF_B1F, nullptr, PT, QT);
    edgeconv_kernel<<<BATCH*NPTS, 128, 0, stream>>>(PT, QT, IDX, ws + OFF_W2T,
                                                    ws + OFF_B2F, AGG);
    // note: q GEMM before k/v would overwrite PT while edgeconv needs it — edgeconv already done.
    gemm_dual_kernel<<<BATCH*NPTS/8, 128, 0, stream>>>(YT, ws + OFF_WKT, ws + OFF_WVT,
                                                       bk, bv, KA, VA);
    gemmT_kernel<128,128,false,false,false,false><<<BATCH*NPTS/8, 128, 0, stream>>>(
        AGG, nullptr, ws + OFF_WQT, bq, nullptr, QA);
    attn_kernel<<<dim3(NPTS/8, NHEAD, BATCH), 256, 0, stream>>>(QA, KA, VA, ADD);
    gemmT_kernel<128,128,false,false,false,false><<<BATCH*NPTS/8, 128, 0, stream>>>(
        ADD, nullptr, ws + OFF_WMHT, bmh, nullptr, MH);
    gemmT_kernel<256,256,true,false,false,true><<<BATCH*NPTS/8, 256, 0, stream>>>(
        AGG, MH, ws + OFF_WC1T, ws + OFF_BC1F, nullptr, TT);
    gemmT_kernel<256,128,false,true,true,false><<<BATCH*NPTS/8, 128, 0, stream>>>(
        TT, nullptr, ws + OFF_WC2T, bc2, AGG, out);
}